// Round 3
// baseline (632.320 us; speedup 1.0000x reference)
//
#include <hip/hip_runtime.h>
#include <hip/hip_bf16.h>

using f32x4 = __attribute__((ext_vector_type(4))) float;
using s16x8 = __attribute__((ext_vector_type(8))) short;

#define DEVFN static __device__ __forceinline__

static constexpr int NCOL = 256;
static constexpr int MROWS = 8192;
static constexpr int BM = 64;
static constexpr int BK = 64;
static constexpr int THREADS = 512;  // 8 waves: 4 wm x 2 wn
static constexpr int KSPLIT = 4;
static constexpr int NTILE = MROWS / BM;   // 128

DEVFN unsigned short f2bf(float f) {
  union { float f; unsigned u; } x; x.f = f;
  unsigned u = x.u;
  u += 0x7fffu + ((u >> 16) & 1u);   // RNE
  return (unsigned short)(u >> 16);
}

DEVFN s16x8 pack8(f32x4 v0, f32x4 v1) {
  union { s16x8 v; unsigned short u[8]; } pk;
  pk.u[0] = f2bf(v0[0]); pk.u[1] = f2bf(v0[1]);
  pk.u[2] = f2bf(v0[2]); pk.u[3] = f2bf(v0[3]);
  pk.u[4] = f2bf(v1[0]); pk.u[5] = f2bf(v1[1]);
  pk.u[6] = f2bf(v1[2]); pk.u[7] = f2bf(v1[3]);
  return pk.v;
}

DEVFN void async16(void* lds, const void* g) {
  __builtin_amdgcn_global_load_lds((const __attribute__((address_space(1))) unsigned*)g,
                                   (__attribute__((address_space(3))) unsigned*)lds,
                                   16, 0, 0);
}

// C[M,256] = A[M,K] @ B[K,256].  A f32 row-major (fragments loaded straight to
// registers, cvt to bf16 at use).  B bf16 in P8 layout:
//   element (k,j) at ((k>>3)*256 + j)*8 + (k&7)
// B staged to LDS 2 tiles deep with counted vmcnt (never 0 mid-loop) + raw
// barriers.  Writes f32 partials Cpart[kh][M][256].
__global__ __launch_bounds__(THREADS, 4)
void gemm_f32(const float* __restrict__ A, int Kfull,
              const unsigned short* __restrict__ Bp8,
              float* __restrict__ Cpart)
{
  __shared__ __align__(16) unsigned short Bb[2][16384];   // 2 x 32KB

  const int q = (NTILE * KSPLIT) / 8;                     // 64
  const int logical = (blockIdx.x & 7) * q + (blockIdx.x >> 3);  // XCD-chunked
  const int kh = logical / NTILE;
  const int tile = logical % NTILE;

  const int klen = Kfull / KSPLIT;
  const int nt = klen / BK;
  const int k0 = kh * klen;
  const int tid = threadIdx.x;
  const int lane = tid & 63;
  const int wm = (tid >> 6) >> 1;   // 0..3 (16 rows each)
  const int wn = (tid >> 6) & 1;    // 0..1 (128 cols each)
  const int lr = lane & 15, lg = lane >> 4;

  // this thread's A fragment row; per tile it loads k-chunks {lg*8..+8} and {32+lg*8..+8}
  const float* Arow = A + (size_t)(tile * BM + wm * 16 + lr) * Kfull + k0 + lg * 8;

  auto stageB = [&](int buf, int t) {
    const unsigned short* src = Bp8 + (size_t)(k0 + t * BK) * NCOL + tid * 8;
#pragma unroll
    for (int o = 0; o < 4; ++o)
      async16(&Bb[buf][o * 4096 + tid * 8], src + o * 4096);
  };

  f32x4 acc[8] = {};
  f32x4 a0, a1, a2, a3;

  // prologue: B(0), A(0), B(1)  (FIFO order matters for the counted waits)
  stageB(0, 0);
  { const float* p = Arow;
    a0 = *(const f32x4*)p;        a1 = *(const f32x4*)(p + 4);
    a2 = *(const f32x4*)(p + 32); a3 = *(const f32x4*)(p + 36); }
  if (nt > 1) stageB(1, 1);

#define GW_ITER(T, BUF)                                                        \
  {                                                                            \
    if ((T) < nt - 1) asm volatile("s_waitcnt vmcnt(4)" ::: "memory");         \
    else              asm volatile("s_waitcnt vmcnt(0)" ::: "memory");         \
    __builtin_amdgcn_s_barrier();          /* B(T) visible in LDS for all */   \
    s16x8 abf0 = pack8(a0, a1), abf1 = pack8(a2, a3);                          \
    if ((T) + 1 < nt) { const float* p = Arow + ((T) + 1) * BK;                \
      a0 = *(const f32x4*)p;        a1 = *(const f32x4*)(p + 4);               \
      a2 = *(const f32x4*)(p + 32); a3 = *(const f32x4*)(p + 36); }            \
    s16x8 b0[8], b1[8];                                                        \
    _Pragma("unroll")                                                          \
    for (int fn = 0; fn < 8; ++fn)                                             \
      b0[fn] = *(const s16x8*)&Bb[BUF][lg * 2048 + (wn * 128 + fn * 16 + lr) * 8]; \
    _Pragma("unroll")                                                          \
    for (int fn = 0; fn < 8; ++fn)                                             \
      acc[fn] = __builtin_amdgcn_mfma_f32_16x16x32_bf16(abf0, b0[fn], acc[fn], 0, 0, 0); \
    _Pragma("unroll")                                                          \
    for (int fn = 0; fn < 8; ++fn)                                             \
      b1[fn] = *(const s16x8*)&Bb[BUF][(4 + lg) * 2048 + (wn * 128 + fn * 16 + lr) * 8]; \
    asm volatile("s_waitcnt lgkmcnt(0)" ::: "memory");                         \
    __builtin_amdgcn_s_barrier();          /* everyone done reading BUF */     \
    if ((T) + 2 < nt) stageB(BUF, (T) + 2);                                    \
    _Pragma("unroll")                                                          \
    for (int fn = 0; fn < 8; ++fn)                                             \
      acc[fn] = __builtin_amdgcn_mfma_f32_16x16x32_bf16(abf1, b1[fn], acc[fn], 0, 0, 0); \
  }

  int t = 0;
  while (true) {
    GW_ITER(t, 0); if (++t >= nt) break;
    GW_ITER(t, 1); if (++t >= nt) break;
  }
#undef GW_ITER

  // C/D layout: col = lane&15, row = (lane>>4)*4 + reg
  float* Cout = Cpart + (size_t)kh * MROWS * NCOL
              + (size_t)(tile * BM + wm * 16 + lg * 4) * NCOL + wn * 128 + lr;
#pragma unroll
  for (int fn = 0; fn < 8; ++fn)
#pragma unroll
    for (int r = 0; r < 4; ++r)
      Cout[(size_t)r * NCOL + fn * 16] = acc[fn][r];
}

// ---- small epilogue / conversion kernels -------------------------------

// f32 [K][256] -> P8 bf16
__global__ void k_convert_p8(const float* __restrict__ W, int K,
                             unsigned short* __restrict__ outp) {
  int tid = blockIdx.x * blockDim.x + threadIdx.x;
  if (tid >= K * NCOL / 4) return;
  int j = tid & (NCOL - 1);
  int i0 = (tid >> 8) << 2;
  unsigned short u[4];
#pragma unroll
  for (int r = 0; r < 4; ++r) u[r] = f2bf(W[(size_t)(i0 + r) * NCOL + j]);
  size_t off = ((size_t)(i0 >> 3) * NCOL + j) * 8 + (i0 & 7);
  *(ushort4*)&outp[off] = make_ushort4(u[0], u[1], u[2], u[3]);
}

// sum KSPLIT partials, optional per-row filter scale, write P8 bf16
__global__ void k_reduce_p8(const float* __restrict__ P, const float* __restrict__ filt,
                            unsigned short* __restrict__ outp) {
  int tid = blockIdx.x * blockDim.x + threadIdx.x;
  int j = tid & (NCOL - 1);
  int i0 = (tid >> 8) << 2;
  unsigned short u[4];
#pragma unroll
  for (int r = 0; r < 4; ++r) {
    size_t o = (size_t)(i0 + r) * NCOL + j;
    float v = 0.f;
#pragma unroll
    for (int h = 0; h < KSPLIT; ++h) v += P[(size_t)h * MROWS * NCOL + o];
    if (filt) v *= filt[i0 + r];
    u[r] = f2bf(v);
  }
  size_t off = ((size_t)(i0 >> 3) * NCOL + j) * 8 + (i0 & 7);
  *(ushort4*)&outp[off] = make_ushort4(u[0], u[1], u[2], u[3]);
}

// sum partials, relu, write row-major f32 (A-operand for next GEMM)
__global__ void k_reduce_relu(const float* __restrict__ P, float* __restrict__ h1f) {
  size_t o = (size_t)(blockIdx.x * blockDim.x + threadIdx.x) * 4;
  float4 v = *(const float4*)&P[o];
#pragma unroll
  for (int h = 1; h < KSPLIT; ++h) {
    float4 b = *(const float4*)&P[(size_t)h * MROWS * NCOL + o];
    v.x += b.x; v.y += b.y; v.z += b.z; v.w += b.w;
  }
  v.x = fmaxf(v.x, 0.f); v.y = fmaxf(v.y, 0.f);
  v.z = fmaxf(v.z, 0.f); v.w = fmaxf(v.w, 0.f);
  *(float4*)&h1f[o] = v;
}

// sum partials, write f32 (final output)
__global__ void k_reduce_f32(const float* __restrict__ P, float* __restrict__ out) {
  size_t o = (size_t)(blockIdx.x * blockDim.x + threadIdx.x) * 4;
  float4 v = *(const float4*)&P[o];
#pragma unroll
  for (int h = 1; h < KSPLIT; ++h) {
    float4 b = *(const float4*)&P[(size_t)h * MROWS * NCOL + o];
    v.x += b.x; v.y += b.y; v.z += b.z; v.w += b.w;
  }
  *(float4*)&out[o] = v;
}

extern "C" void kernel_launch(void* const* d_in, const int* in_sizes, int n_in,
                              void* d_out, int out_size, void* d_ws, size_t ws_size,
                              hipStream_t stream) {
  const float* input = (const float*)d_in[0];
  const float* Wv    = (const float*)d_in[1];
  const float* Winv  = (const float*)d_in[2];
  const float* W1    = (const float*)d_in[3];
  const float* W2    = (const float*)d_in[4];
  const float* f1    = (const float*)d_in[5];
  const float* f2    = (const float*)d_in[6];
  float* out = (float*)d_out;

  char* ws = (char*)d_ws;
  float* part         = (float*)(ws);                         // 32MB
  unsigned short* t1p = (unsigned short*)(ws + 0x2000000);    // 4MB each
  unsigned short* s1p = (unsigned short*)(ws + 0x2400000);
  unsigned short* t2p = (unsigned short*)(ws + 0x2800000);
  unsigned short* s2p = (unsigned short*)(ws + 0x2C00000);
  float* h1f          = (float*)(ws + 0x3000000);             // 8MB
  unsigned short* W1p = (unsigned short*)(ws + 0x3800000);
  unsigned short* W2p = (unsigned short*)(ws + 0x3840000);

  dim3 gT(THREADS), gG(NTILE * KSPLIT);                // 512 WGs, 2/CU
  dim3 rT(256), rG(MROWS * NCOL / 4 / 256);            // 2048 WGs

  k_convert_p8<<<dim3(128), rT, 0, stream>>>(W1, 512, W1p);
  k_convert_p8<<<dim3(64),  rT, 0, stream>>>(W2, 256, W2p);

  // t1 = input @ W1
  gemm_f32<<<gG, gT, 0, stream>>>(input, 512, W1p, part);
  k_reduce_p8<<<rG, rT, 0, stream>>>(part, (const float*)nullptr, t1p);
  // s1 = diag(f1) . (Winv @ t1)
  gemm_f32<<<gG, gT, 0, stream>>>(Winv, 8192, t1p, part);
  k_reduce_p8<<<rG, rT, 0, stream>>>(part, f1, s1p);
  // h1 = relu(Wv @ s1), f32
  gemm_f32<<<gG, gT, 0, stream>>>(Wv, 8192, s1p, part);
  k_reduce_relu<<<rG, rT, 0, stream>>>(part, h1f);
  // t2 = h1 @ W2
  gemm_f32<<<gG, gT, 0, stream>>>(h1f, 256, W2p, part);
  k_reduce_p8<<<rG, rT, 0, stream>>>(part, (const float*)nullptr, t2p);
  // s2 = diag(f2) . (Winv @ t2)
  gemm_f32<<<gG, gT, 0, stream>>>(Winv, 8192, t2p, part);
  k_reduce_p8<<<rG, rT, 0, stream>>>(part, f2, s2p);
  // out = Wv @ s2, f32
  gemm_f32<<<gG, gT, 0, stream>>>(Wv, 8192, s2p, part);
  k_reduce_f32<<<rG, rT, 0, stream>>>(part, out);
}

// Round 4
// 599.551 us; speedup vs baseline: 1.0547x; 1.0547x over previous
//
#include <hip/hip_runtime.h>
#include <hip/hip_bf16.h>

using f32x4 = __attribute__((ext_vector_type(4))) float;
using s16x8 = __attribute__((ext_vector_type(8))) short;

#define DEVFN static __device__ __forceinline__

static constexpr int NCOL = 256;
static constexpr int MROWS = 8192;
static constexpr int BM = 32;
static constexpr int BK = 64;
static constexpr int THREADS = 512;      // 8 waves: 2 wm x 4 wn
static constexpr int NTILE = MROWS / BM; // 256 blocks = 1 per CU

DEVFN unsigned short f2bf(float f) {
  union { float f; unsigned u; } x; x.f = f;
  unsigned u = x.u;
  u += 0x7fffu + ((u >> 16) & 1u);   // RNE
  return (unsigned short)(u >> 16);
}

DEVFN s16x8 pack8(f32x4 v0, f32x4 v1) {
  union { s16x8 v; unsigned short u[8]; } pk;
  pk.u[0] = f2bf(v0[0]); pk.u[1] = f2bf(v0[1]);
  pk.u[2] = f2bf(v0[2]); pk.u[3] = f2bf(v0[3]);
  pk.u[4] = f2bf(v1[0]); pk.u[5] = f2bf(v1[1]);
  pk.u[6] = f2bf(v1[2]); pk.u[7] = f2bf(v1[3]);
  return pk.v;
}

DEVFN void async16(void* lds, const void* g) {
  __builtin_amdgcn_global_load_lds((const __attribute__((address_space(1))) unsigned*)g,
                                   (__attribute__((address_space(3))) unsigned*)lds,
                                   16, 0, 0);
}

// C[M,256] = A[M,K] @ B[K,256], full K per block (no split-K).
// A f32 row-major, staged to LDS via global_load_lds (XOR-swizzled source,
// linear dest), converted to bf16 at fragment read.
// B bf16 in P8 layout: element (k,j) at ((k>>3)*256 + j)*8 + (k&7)  -> each
// 64-k tile is a contiguous 32KB block, staged linearly.
// 3-deep pipeline, counted vmcnt (10 = 2 tiles x 5 ops in flight), raw
// s_barrier, no drains mid-loop.
// EPI: 0 = P8 bf16 out, 1 = P8 bf16 out scaled by filt[row],
//      2 = f32 row-major relu, 3 = f32 row-major.
template<int EPI>
__global__ __launch_bounds__(THREADS)
void gemm32(const float* __restrict__ A, int Kfull,
            const unsigned short* __restrict__ Bp8,
            const float* __restrict__ filt, void* __restrict__ Out)
{
  __shared__ __align__(16) float Af[3][BM * BK];            // 3 x 8KB
  __shared__ __align__(16) unsigned short Bb[3][BK * NCOL]; // 3 x 32KB -> 120KB total

  const int tile = blockIdx.x;
  const int nt = Kfull / BK;
  const int tid = threadIdx.x;
  const int lane = tid & 63;
  const int wm = (tid >> 6) >> 2;   // 0..1 (16 rows each)
  const int wn = (tid >> 6) & 3;    // 0..3 (64 cols each)
  const int lr = lane & 15, lg = lane >> 4;

  const int srow = tid >> 4;        // 0..31 A-stage row
  const int schunk = tid & 15;      // 16B chunk in the 256B k-window
  const int scs = schunk ^ (srow & 7);   // pre-swizzled SOURCE chunk

  auto stage = [&](int buf, int t) {   // 5 VMEM ops per thread
    const char* asrc = (const char*)(A + (size_t)(tile * BM + srow) * Kfull + t * BK)
                       + scs * 16;
    async16(&Af[buf][tid * 4], asrc);
    const unsigned short* bsrc = Bp8 + (size_t)t * (BK * NCOL) + tid * 8;
#pragma unroll
    for (int o = 0; o < 4; ++o)
      async16(&Bb[buf][o * 4096 + tid * 8], bsrc + o * 4096);
  };

  stage(0, 0);
  if (nt > 1) stage(1, 1);
  if (nt > 2) stage(2, 2);

  f32x4 acc[4] = {};
  int bcur = 0;
  for (int t = 0; t < nt; ++t) {
    // stages in flight after this wait: min(2, nt-1-t) -> ensure stage(t) landed
    if (t + 3 <= nt)      asm volatile("s_waitcnt vmcnt(10)");
    else if (t + 2 <= nt) asm volatile("s_waitcnt vmcnt(5)");
    else                  asm volatile("s_waitcnt vmcnt(0)");
    __builtin_amdgcn_s_barrier();
    __builtin_amdgcn_sched_barrier(0);

    f32x4 av[2][2];
    s16x8 bv[2][4];
#pragma unroll
    for (int s = 0; s < 2; ++s) {
      const int r = wm * 16 + lr;
      const int c0 = s * 8 + lg * 2;
      av[s][0] = *(const f32x4*)&Af[bcur][r * 64 + (((c0    ) ^ (r & 7)) * 4)];
      av[s][1] = *(const f32x4*)&Af[bcur][r * 64 + (((c0 + 1) ^ (r & 7)) * 4)];
      const int kc = s * 4 + lg;
#pragma unroll
      for (int fn = 0; fn < 4; ++fn)
        bv[s][fn] = *(const s16x8*)&Bb[bcur][kc * 2048 + (wn * 64 + fn * 16 + lr) * 8];
    }
    __builtin_amdgcn_sched_barrier(0);
    asm volatile("s_waitcnt lgkmcnt(0)");
    __builtin_amdgcn_s_barrier();          // all waves done reading buf bcur
    if (t + 3 < nt) stage(bcur, t + 3);    // refill freed buffer

#pragma unroll
    for (int s = 0; s < 2; ++s) {          // register-only: overlaps the stage
      s16x8 abf = pack8(av[s][0], av[s][1]);
#pragma unroll
      for (int fn = 0; fn < 4; ++fn)
        acc[fn] = __builtin_amdgcn_mfma_f32_16x16x32_bf16(abf, bv[s][fn], acc[fn], 0, 0, 0);
    }
    bcur = (bcur == 2) ? 0 : bcur + 1;
  }

  // C/D layout: col = lane&15, row = (lane>>4)*4 + reg
  const int r0 = tile * BM + wm * 16 + lg * 4;
  const int colb = wn * 64 + lr;
  if constexpr (EPI <= 1) {
    float fs[4] = {1.f, 1.f, 1.f, 1.f};
    if constexpr (EPI == 1) {
#pragma unroll
      for (int r = 0; r < 4; ++r) fs[r] = filt[r0 + r];
    }
    unsigned short* Op = (unsigned short*)Out;
    const size_t base = (size_t)(r0 >> 3) * 2048 + (r0 & 7);  // ((r0>>3)*256)*8 + r0&7
#pragma unroll
    for (int fn = 0; fn < 4; ++fn) {
      ushort4 u;
      u.x = f2bf(acc[fn][0] * fs[0]);
      u.y = f2bf(acc[fn][1] * fs[1]);
      u.z = f2bf(acc[fn][2] * fs[2]);
      u.w = f2bf(acc[fn][3] * fs[3]);
      *(ushort4*)&Op[base + (size_t)(colb + fn * 16) * 8] = u;
    }
  } else {
    float* O = (float*)Out;
#pragma unroll
    for (int fn = 0; fn < 4; ++fn)
#pragma unroll
      for (int r = 0; r < 4; ++r) {
        float v = acc[fn][r];
        if constexpr (EPI == 2) v = fmaxf(v, 0.f);
        O[(size_t)(r0 + r) * NCOL + colb + fn * 16] = v;
      }
  }
}

// f32 [K][256] -> P8 bf16 (for W1, W2)
__global__ void k_convert_p8(const float* __restrict__ W, int K,
                             unsigned short* __restrict__ outp) {
  int tid = blockIdx.x * blockDim.x + threadIdx.x;
  if (tid >= K * NCOL / 4) return;
  int j = tid & (NCOL - 1);
  int i0 = (tid >> 8) << 2;
  unsigned short u[4];
#pragma unroll
  for (int r = 0; r < 4; ++r) u[r] = f2bf(W[(size_t)(i0 + r) * NCOL + j]);
  size_t off = ((size_t)(i0 >> 3) * NCOL + j) * 8 + (i0 & 7);
  *(ushort4*)&outp[off] = make_ushort4(u[0], u[1], u[2], u[3]);
}

extern "C" void kernel_launch(void* const* d_in, const int* in_sizes, int n_in,
                              void* d_out, int out_size, void* d_ws, size_t ws_size,
                              hipStream_t stream) {
  const float* input = (const float*)d_in[0];
  const float* Wv    = (const float*)d_in[1];
  const float* Winv  = (const float*)d_in[2];
  const float* W1    = (const float*)d_in[3];
  const float* W2    = (const float*)d_in[4];
  const float* f1    = (const float*)d_in[5];
  const float* f2    = (const float*)d_in[6];
  float* out = (float*)d_out;

  char* ws = (char*)d_ws;
  unsigned short* t1p = (unsigned short*)(ws);               // 4MB each, P8
  unsigned short* s1p = (unsigned short*)(ws + 0x400000);
  unsigned short* t2p = (unsigned short*)(ws + 0x800000);
  unsigned short* s2p = (unsigned short*)(ws + 0xC00000);
  float* h1f          = (float*)(ws + 0x1000000);            // 8MB row-major f32
  unsigned short* W1p = (unsigned short*)(ws + 0x1800000);   // 256KB
  unsigned short* W2p = (unsigned short*)(ws + 0x1840000);   // 128KB

  dim3 gT(THREADS), gG(NTILE);                               // 256 WGs = 1/CU

  k_convert_p8<<<dim3(128), dim3(256), 0, stream>>>(W1, 512, W1p);
  k_convert_p8<<<dim3(64),  dim3(256), 0, stream>>>(W2, 256, W2p);

  // t1 = input @ W1                      -> P8
  gemm32<0><<<gG, gT, 0, stream>>>(input, 512, W1p, nullptr, t1p);
  // s1 = diag(f1) . (Winv @ t1)          -> P8, fused filter scale
  gemm32<1><<<gG, gT, 0, stream>>>(Winv, 8192, t1p, f1, s1p);
  // h1 = relu(Wv @ s1)                   -> f32 row-major
  gemm32<2><<<gG, gT, 0, stream>>>(Wv, 8192, s1p, nullptr, h1f);
  // t2 = h1 @ W2                         -> P8
  gemm32<0><<<gG, gT, 0, stream>>>(h1f, 256, W2p, nullptr, t2p);
  // s2 = diag(f2) . (Winv @ t2)          -> P8, fused filter scale
  gemm32<1><<<gG, gT, 0, stream>>>(Winv, 8192, t2p, f2, s2p);
  // out = Wv @ s2                        -> f32
  gemm32<3><<<gG, gT, 0, stream>>>(Wv, 8192, s2p, nullptr, out);
}

// Round 5
// 449.272 us; speedup vs baseline: 1.4074x; 1.3345x over previous
//
#include <hip/hip_runtime.h>
#include <hip/hip_bf16.h>

using f32x4 = __attribute__((ext_vector_type(4))) float;
using s16x8 = __attribute__((ext_vector_type(8))) short;

#define DEVFN static __device__ __forceinline__

static constexpr int NCOL = 256;
static constexpr int MROWS = 8192;
static constexpr int BM = 64;
static constexpr int BK = 64;
static constexpr int THREADS = 512;       // 8 waves, each owns 64 rows x 32 cols
static constexpr int NTILE = MROWS / BM;  // 128

DEVFN unsigned short f2bf(float f) {
  union { float f; unsigned u; } x; x.f = f;
  unsigned u = x.u;
  u += 0x7fffu + ((u >> 16) & 1u);   // RNE
  return (unsigned short)(u >> 16);
}

DEVFN s16x8 pack8(f32x4 v0, f32x4 v1) {
  union { s16x8 v; unsigned short u[8]; } pk;
  pk.u[0] = f2bf(v0[0]); pk.u[1] = f2bf(v0[1]);
  pk.u[2] = f2bf(v0[2]); pk.u[3] = f2bf(v0[3]);
  pk.u[4] = f2bf(v1[0]); pk.u[5] = f2bf(v1[1]);
  pk.u[6] = f2bf(v1[2]); pk.u[7] = f2bf(v1[3]);
  return pk.v;
}

// C[M,256] = A[M,K] @ B[K,256].
//  A row-major (f32 if AF32 else bf16). Reg-staged: global->reg, cvt once,
//  swizzled ds_write_b128 into an 8KB bf16 LDS tile (dbuf). WB: also write
//  the bf16 copy to Awb (row-major) for cheap reuse.
//  B bf16 in P8 layout: elem (k,j) at ((k>>3)*256+j)*8+(k&7). Fragments are
//  16B-contiguous -> loaded DIRECTLY global->reg (L2-hot panel), never LDS,
//  never inside the barrier path.
//  KS-way split-K. EPI 0: f32 partials Cpart[kh][M][256]. EPI 1 (KS=1 only):
//  direct P8 bf16 output.
template<bool AF32, bool WB, int KS, int EPI>
__global__ __launch_bounds__(THREADS, 4)
void gemm_bd(const void* __restrict__ Aany, int Kfull,
             const unsigned short* __restrict__ Bp8,
             float* __restrict__ Cpart, unsigned short* __restrict__ Pout,
             unsigned short* __restrict__ Awb)
{
  __shared__ __align__(16) unsigned short As[2][BM * BK];   // 2 x 8KB

  const int nwg = NTILE * KS;
  const int q = nwg / 8;
  const int logical = (blockIdx.x & 7) * q + (blockIdx.x >> 3);  // XCD-chunked
  const int kh = logical >> 7;          // logical / NTILE
  const int tile = logical & 127;       // logical % NTILE

  const int klen = Kfull / KS;
  const int nt = klen / BK;
  const int k0 = kh * klen;
  const int tid = threadIdx.x;
  const int lane = tid & 63;
  const int wn = tid >> 6;              // 0..7, cols wn*32..+32
  const int lr = lane & 15, lg = lane >> 4;
  const int srow = tid >> 3;            // 0..63  (A-stage row)
  const int schunk = tid & 7;           // 8-elem k-chunk

  const char* Ab = (const char*)Aany;

  auto loadA = [&](int t) -> s16x8 {
    if constexpr (AF32) {
      const float* p = (const float*)Ab + (size_t)(tile * BM + srow) * Kfull
                       + k0 + t * BK + schunk * 8;
      return pack8(*(const f32x4*)p, *(const f32x4*)(p + 4));
    } else {
      return *(const s16x8*)((const unsigned short*)Ab
             + (size_t)(tile * BM + srow) * Kfull + k0 + t * BK + schunk * 8);
    }
  };
  auto putA = [&](int buf, int t, s16x8 pk) {
    *(s16x8*)&As[buf][srow * 64 + ((schunk ^ (srow & 7)) * 8)] = pk;
    if constexpr (WB)
      *(s16x8*)&Awb[(size_t)(tile * BM + srow) * Kfull + k0 + t * BK + schunk * 8] = pk;
  };
  auto loadB = [&](int t, s16x8 bf[2][2]) {
    const size_t kb = (size_t)(k0 + t * BK) >> 3;
#pragma unroll
    for (int s = 0; s < 2; ++s)
#pragma unroll
      for (int fn = 0; fn < 2; ++fn)
        bf[s][fn] = *(const s16x8*)&Bp8[((kb + s * 4 + lg) * 256
                                         + wn * 32 + fn * 16 + lr) * 8];
  };

  f32x4 acc[4][2] = {};
  s16x8 b0[2][2], b1[2][2];

  { s16x8 a0 = loadA(0); loadB(0, b0); putA(0, 0, a0); }
  __syncthreads();

#define GW_ITER(BC, BN, CUR)                                                   \
  {                                                                            \
    const bool pre = (t + 1 < nt);                                             \
    s16x8 an;                                                                  \
    if (pre) { an = loadA(t + 1); loadB(t + 1, BN); }                          \
    _Pragma("unroll")                                                          \
    for (int s = 0; s < 2; ++s) {                                              \
      s16x8 af[4];                                                             \
      _Pragma("unroll")                                                        \
      for (int fm = 0; fm < 4; ++fm) {                                         \
        const int r = fm * 16 + lr, c = s * 4 + lg;                            \
        af[fm] = *(const s16x8*)&As[CUR][r * 64 + ((c ^ (r & 7)) * 8)];        \
      }                                                                        \
      if (s == 0 && pre) putA(CUR ^ 1, t + 1, an);                             \
      _Pragma("unroll")                                                        \
      for (int fm = 0; fm < 4; ++fm)                                           \
        _Pragma("unroll")                                                      \
        for (int fn = 0; fn < 2; ++fn)                                         \
          acc[fm][fn] = __builtin_amdgcn_mfma_f32_16x16x32_bf16(               \
              af[fm], BC[s][fn], acc[fm][fn], 0, 0, 0);                        \
    }                                                                          \
    __syncthreads();                                                           \
  }

  int t = 0;
  while (true) {
    GW_ITER(b0, b1, 0); if (++t >= nt) break;
    GW_ITER(b1, b0, 1); if (++t >= nt) break;
  }
#undef GW_ITER

  // C/D layout: col = lane&15, row = (lane>>4)*4 + reg
  if constexpr (EPI == 0) {
    float* Co = Cpart + (size_t)kh * MROWS * NCOL;
#pragma unroll
    for (int fm = 0; fm < 4; ++fm)
#pragma unroll
      for (int fn = 0; fn < 2; ++fn)
#pragma unroll
        for (int r = 0; r < 4; ++r)
          Co[(size_t)(tile * BM + fm * 16 + lg * 4 + r) * NCOL
             + wn * 32 + fn * 16 + lr] = acc[fm][fn][r];
  } else {
    // direct P8 bf16 (KS==1): output row is the next GEMM's k index
#pragma unroll
    for (int fm = 0; fm < 4; ++fm) {
      const int row0 = tile * BM + fm * 16 + lg * 4;
#pragma unroll
      for (int fn = 0; fn < 2; ++fn) {
        const int col = wn * 32 + fn * 16 + lr;
        ushort4 u;
        u.x = f2bf(acc[fm][fn][0]); u.y = f2bf(acc[fm][fn][1]);
        u.z = f2bf(acc[fm][fn][2]); u.w = f2bf(acc[fm][fn][3]);
        *(ushort4*)&Pout[((size_t)(row0 >> 3) * 256 + col) * 8 + (row0 & 7)] = u;
      }
    }
  }
}

// ---- small conversion / reduce kernels ---------------------------------

// f32 [K][256] -> P8 bf16
__global__ void k_convert_p8(const float* __restrict__ W, int K,
                             unsigned short* __restrict__ outp) {
  int tid = blockIdx.x * blockDim.x + threadIdx.x;
  if (tid >= K * NCOL / 4) return;
  int j = tid & (NCOL - 1);
  int i0 = (tid >> 8) << 2;
  unsigned short u[4];
#pragma unroll
  for (int r = 0; r < 4; ++r) u[r] = f2bf(W[(size_t)(i0 + r) * NCOL + j]);
  size_t off = ((size_t)(i0 >> 3) * NCOL + j) * 8 + (i0 & 7);
  *(ushort4*)&outp[off] = make_ushort4(u[0], u[1], u[2], u[3]);
}

// sum 4 partials, optional per-row filter scale, write P8 bf16
__global__ void k_reduce_p8(const float* __restrict__ P, const float* __restrict__ filt,
                            unsigned short* __restrict__ outp) {
  int tid = blockIdx.x * blockDim.x + threadIdx.x;
  int j = tid & (NCOL - 1);
  int i0 = (tid >> 8) << 2;
  unsigned short u[4];
#pragma unroll
  for (int r = 0; r < 4; ++r) {
    size_t o = (size_t)(i0 + r) * NCOL + j;
    float v = P[o] + P[(size_t)MROWS * NCOL + o]
            + P[2 * (size_t)MROWS * NCOL + o] + P[3 * (size_t)MROWS * NCOL + o];
    if (filt) v *= filt[i0 + r];
    u[r] = f2bf(v);
  }
  size_t off = ((size_t)(i0 >> 3) * NCOL + j) * 8 + (i0 & 7);
  *(ushort4*)&outp[off] = make_ushort4(u[0], u[1], u[2], u[3]);
}

// sum 4 partials, relu, write row-major bf16 (A operand of next GEMM)
__global__ void k_reduce_relu_bf16(const float* __restrict__ P,
                                   unsigned short* __restrict__ h1b) {
  size_t o = (size_t)(blockIdx.x * blockDim.x + threadIdx.x) * 4;
  float4 a = *(const float4*)&P[o];
  float4 b = *(const float4*)&P[(size_t)MROWS * NCOL + o];
  float4 c = *(const float4*)&P[2 * (size_t)MROWS * NCOL + o];
  float4 d = *(const float4*)&P[3 * (size_t)MROWS * NCOL + o];
  ushort4 u;
  u.x = f2bf(fmaxf(a.x + b.x + c.x + d.x, 0.f));
  u.y = f2bf(fmaxf(a.y + b.y + c.y + d.y, 0.f));
  u.z = f2bf(fmaxf(a.z + b.z + c.z + d.z, 0.f));
  u.w = f2bf(fmaxf(a.w + b.w + c.w + d.w, 0.f));
  *(ushort4*)&h1b[o] = u;
}

// sum 4 partials, write f32 (final output)
__global__ void k_reduce_f32(const float* __restrict__ P, float* __restrict__ out) {
  size_t o = (size_t)(blockIdx.x * blockDim.x + threadIdx.x) * 4;
  float4 a = *(const float4*)&P[o];
  float4 b = *(const float4*)&P[(size_t)MROWS * NCOL + o];
  float4 c = *(const float4*)&P[2 * (size_t)MROWS * NCOL + o];
  float4 d = *(const float4*)&P[3 * (size_t)MROWS * NCOL + o];
  float4 v; v.x = a.x + b.x + c.x + d.x; v.y = a.y + b.y + c.y + d.y;
  v.z = a.z + b.z + c.z + d.z; v.w = a.w + b.w + c.w + d.w;
  *(float4*)&out[o] = v;
}

extern "C" void kernel_launch(void* const* d_in, const int* in_sizes, int n_in,
                              void* d_out, int out_size, void* d_ws, size_t ws_size,
                              hipStream_t stream) {
  const float* input = (const float*)d_in[0];
  const float* Wv    = (const float*)d_in[1];
  const float* Winv  = (const float*)d_in[2];
  const float* W1    = (const float*)d_in[3];
  const float* W2    = (const float*)d_in[4];
  const float* f1    = (const float*)d_in[5];
  const float* f2    = (const float*)d_in[6];
  float* out = (float*)d_out;

  char* ws = (char*)d_ws;
  unsigned short* WvBf   = (unsigned short*)(ws);                 // 128MB
  unsigned short* WinvBf = (unsigned short*)(ws + 0x8000000);     // 128MB
  float* part            = (float*)(ws + 0x10000000);             // 32MB
  unsigned short* W1p    = (unsigned short*)(ws + 0x12000000);    // 256KB
  unsigned short* W2p    = (unsigned short*)(ws + 0x12040000);    // 128KB
  unsigned short* t1p    = (unsigned short*)(ws + 0x12060000);    // 4MB each
  unsigned short* s1p    = (unsigned short*)(ws + 0x12460000);
  unsigned short* t2p    = (unsigned short*)(ws + 0x12860000);
  unsigned short* s2p    = (unsigned short*)(ws + 0x12C60000);
  unsigned short* h1b    = (unsigned short*)(ws + 0x13060000);    // 4MB bf16

  dim3 gT(THREADS);
  dim3 gBig(NTILE * 4);                                // 512 WGs, 2/CU
  dim3 gSmall(NTILE);                                  // 128 WGs
  dim3 rT(256), rG(MROWS * NCOL / 4 / 256);            // 2048 WGs

  k_convert_p8<<<dim3(128), rT, 0, stream>>>(W1, 512, W1p);
  k_convert_p8<<<dim3(64),  rT, 0, stream>>>(W2, 256, W2p);

  // t1 = input @ W1                       (f32 A, KS=1, direct P8)
  gemm_bd<true, false, 1, 1><<<gSmall, gT, 0, stream>>>(
      (const void*)input, 512, W1p, nullptr, t1p, nullptr);
  // s1 = diag(f1).(Winv @ t1)             (f32 A + bf16 writeback)
  gemm_bd<true, true, 4, 0><<<gBig, gT, 0, stream>>>(
      (const void*)Winv, 8192, t1p, part, nullptr, WinvBf);
  k_reduce_p8<<<rG, rT, 0, stream>>>(part, f1, s1p);
  // h1 = relu(Wv @ s1)                    (f32 A + bf16 writeback)
  gemm_bd<true, true, 4, 0><<<gBig, gT, 0, stream>>>(
      (const void*)Wv, 8192, s1p, part, nullptr, WvBf);
  k_reduce_relu_bf16<<<rG, rT, 0, stream>>>(part, h1b);
  // t2 = h1 @ W2                          (bf16 A, KS=1, direct P8)
  gemm_bd<false, false, 1, 1><<<gSmall, gT, 0, stream>>>(
      (const void*)h1b, 256, W2p, nullptr, t2p, nullptr);
  // s2 = diag(f2).(Winv @ t2)             (bf16 A copy)
  gemm_bd<false, false, 4, 0><<<gBig, gT, 0, stream>>>(
      (const void*)WinvBf, 8192, t2p, part, nullptr, nullptr);
  k_reduce_p8<<<rG, rT, 0, stream>>>(part, f2, s2p);
  // out = Wv @ s2                         (bf16 A copy, f32 out)
  gemm_bd<false, false, 4, 0><<<gBig, gT, 0, stream>>>(
      (const void*)WvBf, 8192, s2p, part, nullptr, nullptr);
  k_reduce_f32<<<rG, rT, 0, stream>>>(part, out);
}